// Round 4
// baseline (268.341 us; speedup 1.0000x reference)
//
#include <hip/hip_runtime.h>

#define HID 50
#define IND 8
#define TLEN 512
#define NB 16        // batch columns per block — all 16 MFMA N cols real
#define CH 128       // x chunk timesteps staged in LDS (4 chunks/sequence)
#define XTS 136      // x_frag per-timestep stride in halves (272B: 17*16B)
#define NTHR 256     // 4 waves, 4 M-tiles each (tiles 0..15; 14 real, 2 self-zero)

typedef _Float16 f16x8 __attribute__((ext_vector_type(8)));
typedef _Float16 f16x4 __attribute__((ext_vector_type(4)));
typedef _Float16 f16x2 __attribute__((ext_vector_type(2)));
typedef float f32x4 __attribute__((ext_vector_type(4)));

// Round-14: 4 waves x 4 M-tiles — one wave per SIMD, deep per-wave ILP.
//  R3 evidence: conflicts -3.2x and VALU -20% each moved the 806-cyc step
//  interval <3%. The interval is lockstep phase latency (exposed ds_read,
//  MFMA dep chain, serial gate chain), not throughput. Fix: give each wave
//  4 independent tile-chains so its own issue stream hides the latency:
//  - 8 MFMAs fed by the SAME 2 ds_read_b128 (8 reads/step total, was 14)
//  - 4 independent gate evals (trans pipe stays fed, dep chains interleave)
//  - 2 packed b32 h-writes/lane (pairs land adjacent by the P permutation)
//  - barrier pool 7 -> 4 waves; 1 wave/SIMD (no lockstep collision)
//  - wave 3 tiles 14,15: zero-A + zero-bias => h stays 0; kgrp 7 (x rows)
//    write suppressed by wave-uniform branch
__global__ __launch_bounds__(NTHR, 1) void gru_mfma10(
    const float* __restrict__ x,      // [B, T, 8]
    const float* __restrict__ W_ih,   // [150, 8]
    const float* __restrict__ W_hh,   // [150, 50]
    const float* __restrict__ b_ih,   // [150]
    const float* __restrict__ b_hh,   // [150]
    const float* __restrict__ W_out,  // [1, 50]
    const float* __restrict__ b_out,  // [1]
    float* __restrict__ out)          // [B]
{
    const int tid  = threadIdx.x;     // 256 threads = 4 waves
    const int wave = tid >> 6;
    const int lane = tid & 63;
    const int m16  = lane & 15;
    const int quad = lane >> 4;
    const int bb   = blockIdx.x;

    // B buffers: 2 x [7 kgrps][16 slots][8 halves] = 2 x 896 halves
    __shared__ _Float16 B_lds[2 * 896];
    __shared__ _Float16 x_frag[CH * XTS];     // ~34.8 KB fragment-ordered x
    __shared__ float    red[NB * 56];         // head scratch

    // intra-slot k permutation: half index hp holds k-offset P[hp]
    const int P[8] = {0, 4, 1, 5, 2, 6, 3, 7};

    // ---- one-time: A fragments + biases into VGPRs, scales prefolded ----
    auto aval = [&](int tt, int k) -> float {
        const int R  = 16 * tt + m16;
        const int rj = R >> 2;
        const int g  = R & 3;
        if (rj >= HID) return 0.f;
        const float sc = (g <= 1) ? -1.44269504f : 2.88539008f;
        float w = 0.f;
        if (g <= 1) {
            if (k < HID)      w = W_hh[(g * HID + rj) * HID + k];
            else if (k >= 56) w = W_ih[(g * HID + rj) * IND + (k - 56)];
        } else if (g == 2) {
            if (k < HID)      w = W_hh[(2 * HID + rj) * HID + k];
        } else {
            if (k >= 56)      w = W_ih[(2 * HID + rj) * IND + (k - 56)];
        }
        return sc * w;
    };

    f16x8 a0[4], a1[4];
#pragma unroll
    for (int p = 0; p < 4; ++p) {
        const int tt = 4 * wave + p;
#pragma unroll
        for (int j = 0; j < 8; ++j) {
            a0[p][j] = (_Float16)aval(tt, quad * 8 + P[j]);
            a1[p][j] = (_Float16)aval(tt, 32 + quad * 8 + P[j]);
        }
    }

    f32x4 bias[4];
#pragma unroll
    for (int p = 0; p < 4; ++p) {
        const int jh = 16 * wave + 4 * p + quad;
        f32x4 b = {0.f, 0.f, 0.f, 0.f};
        if (jh < HID) {
            b[0] = -1.44269504f * (b_ih[jh] + b_hh[jh]);
            b[1] = -1.44269504f * (b_ih[HID + jh] + b_hh[HID + jh]);
            b[2] =  2.88539008f * b_hh[2 * HID + jh];
            b[3] =  2.88539008f * b_ih[2 * HID + jh];
        }
        bias[p] = b;
    }

    float h[4] = {0.f, 0.f, 0.f, 0.f};

    // ---- x chunk staging: fragment order, permuted intra-slot ----
    auto stage_chunk = [&](int c) {
        for (int u = tid; u < NB * CH; u += NTHR) {      // 2048 units
            const int n    = u >> 7;
            const int trel = u & (CH - 1);
            const float4* s = (const float4*)(x + ((size_t)(bb * NB + n) * TLEN + (size_t)c * CH + trel) * IND);
            const float4 va = s[0];                       // d 0..3
            const float4 vb = s[1];                       // d 4..7
            const f16x4 lo = {(_Float16)va.x, (_Float16)vb.x, (_Float16)va.y, (_Float16)vb.y};
            const f16x4 hi = {(_Float16)va.z, (_Float16)vb.z, (_Float16)va.w, (_Float16)vb.w};
            *(f16x4*)&x_frag[trel * XTS + n * 8]     = lo;
            *(f16x4*)&x_frag[trel * XTS + n * 8 + 4] = hi;
        }
    };

    // ---- init: zero both B buffers; stage chunk 0 ----
    for (int idx = tid; idx < 2 * 896; idx += NTHR)
        B_lds[idx] = (_Float16)0.f;
    stage_chunk(0);
    __syncthreads();

    const int lane8 = lane * 8;                       // halves: lane*16B
    const _Float16* xq = &x_frag[m16 * 8];            // quad3 x base
    // write: pair (h0,h1) -> kgrp 2w halves 2q,2q+1; (h2,h3) -> kgrp 2w+1
    const int wad0 = (2 * wave) * 128 + m16 * 8 + 2 * quad;

    // 5-trans gates (scales prefolded): r = rcp(1+2^c0); Z = 2^c1;
    // E = 2^(c3 + r*c2); h' = (E*(Z+h) + (h-Z)) * rcp((E+1)*(Z+1))
    auto gates = [&](const f32x4& cc, float hh) -> float {
        const float R2 = __builtin_amdgcn_exp2f(cc[0]);
        const float r  = __builtin_amdgcn_rcpf(1.0f + R2);
        const float Z2 = __builtin_amdgcn_exp2f(cc[1]);
        const float E  = __builtin_amdgcn_exp2f(cc[3] + r * cc[2]);
        const float num = E * (Z2 + hh) + (hh - Z2);
        const float den = (E + 1.0f) * (Z2 + 1.0f);
        return num * __builtin_amdgcn_rcpf(den);
    };

    auto step = [&](int i, int cur, int nxt) {
        _Float16* Bc = &B_lds[cur * 896];
        _Float16* Bn = &B_lds[nxt * 896];
        const f16x8 bf0 = *(const f16x8*)(Bc + lane8);
        const _Float16* p1 = (quad == 3) ? (xq + (size_t)i * XTS) : (Bc + 512 + lane8);
        const f16x8 bf1 = *(const f16x8*)p1;
        f32x4 c[4];
#pragma unroll
        for (int p = 0; p < 4; ++p)
            c[p] = __builtin_amdgcn_mfma_f32_16x16x32_f16(a0[p], bf0, bias[p], 0, 0, 0);
#pragma unroll
        for (int p = 0; p < 4; ++p)
            c[p] = __builtin_amdgcn_mfma_f32_16x16x32_f16(a1[p], bf1, c[p], 0, 0, 0);
#pragma unroll
        for (int p = 0; p < 4; ++p)
            h[p] = gates(c[p], h[p]);
        *(f16x2*)(Bn + wad0) = f16x2{(_Float16)h[0], (_Float16)h[1]};
        if (wave < 3)   // wave 3's second pair would hit kgrp 7 = x rows
            *(f16x2*)(Bn + wad0 + 128) = f16x2{(_Float16)h[2], (_Float16)h[3]};
        __syncthreads();
    };

    // ---- recurrence: 4 waves, 1 barrier/step ----
    for (int c = 0; c < 4; ++c) {
        if (c != 0) { stage_chunk(c); __syncthreads(); }
#pragma unroll 4
        for (int i = 0; i < CH; i += 2) {
            step(i,     0, 1);
            step(i + 1, 1, 0);
        }
    }

    // ---- head: out[n] = sum_jh h(jh,n) * W_out[jh] + b_out ----
#pragma unroll
    for (int p = 0; p < 4; ++p) {
        const int jh = 16 * wave + 4 * p + quad;
        if (jh < HID) red[m16 * 56 + jh] = h[p] * W_out[jh];
    }
    __syncthreads();
    if (tid < NB) {
        float s = b_out[0];
        for (int j = 0; j < HID; ++j) s += red[tid * 56 + j];
        out[bb * NB + tid] = s;
    }
}

extern "C" void kernel_launch(void* const* d_in, const int* in_sizes, int n_in,
                              void* d_out, int out_size, void* d_ws, size_t ws_size,
                              hipStream_t stream) {
    const float* x     = (const float*)d_in[0];
    const float* W_ih  = (const float*)d_in[1];
    const float* W_hh  = (const float*)d_in[2];
    const float* b_ih  = (const float*)d_in[3];
    const float* b_hh  = (const float*)d_in[4];
    const float* W_out = (const float*)d_in[5];
    const float* b_out = (const float*)d_in[6];
    float* out = (float*)d_out;

    const int B = in_sizes[0] / (TLEN * IND);   // 4096
    gru_mfma10<<<B / NB, NTHR, 0, stream>>>(x, W_ih, W_hh, b_ih, b_hh, W_out, b_out, out);
}

// Round 5
// 258.923 us; speedup vs baseline: 1.0364x; 1.0364x over previous
//
#include <hip/hip_runtime.h>

#define HID 50
#define IND 8
#define TLEN 512
#define NB 16        // batch columns per block — all 16 MFMA N cols real
#define CH 128       // x chunk timesteps staged in LDS (4 chunks/sequence)
#define XTS 136      // x_frag per-timestep stride in halves (272B: 17*16B)
#define NTHR 512     // 8 waves: 0-6 compute (2 M-tiles each), wave 7 = stager

typedef _Float16 f16x8 __attribute__((ext_vector_type(8)));
typedef _Float16 f16x4 __attribute__((ext_vector_type(4)));
typedef _Float16 f16x2 __attribute__((ext_vector_type(2)));
typedef float f32x4 __attribute__((ext_vector_type(4)));

// Round-15: R4 champion (7 compute waves, fragment-order B, 806 cyc/step)
//  + (a) dedicated stager wave 7: double-buffered x_frag, 2-deep global-load
//        pipeline (issue at js, consume at js+2) -> no chunk bubbles, no
//        staging bursts on compute waves, SIMD3 balanced
//  + (b) unchained MFMA pairs (independent bias-seeded / zero-seeded
//        accumulators + 4 adds/eval) -> MFMA dep latency off critical path
//  R5 lesson encoded: >=2 waves/SIMD required (1 wave/SIMD serializes).
__global__ __launch_bounds__(NTHR, 1) void gru_mfma11(
    const float* __restrict__ x,      // [B, T, 8]
    const float* __restrict__ W_ih,   // [150, 8]
    const float* __restrict__ W_hh,   // [150, 50]
    const float* __restrict__ b_ih,   // [150]
    const float* __restrict__ b_hh,   // [150]
    const float* __restrict__ W_out,  // [1, 50]
    const float* __restrict__ b_out,  // [1]
    float* __restrict__ out)          // [B]
{
    const int tid  = threadIdx.x;     // 512 threads = 8 waves
    const int wave = tid >> 6;
    const int lane = tid & 63;
    const int m16  = lane & 15;
    const int quad = lane >> 4;
    const int bb   = blockIdx.x;

    const int t0  = 2 * wave;         // tiles; R = 16*t + m16; R = 4*jh + g
    const int t1  = 2 * wave + 1;
    const int jh0 = 8 * wave + quad;
    const int jh1 = 8 * wave + 4 + quad;

    // B buffers: 2 x [7 kgrps][16 slots][8 halves] = 2 x 896 halves
    __shared__ _Float16 B_lds[2 * 896];
    __shared__ _Float16 x_frag[2][CH * XTS];  // double-buffered, ~70 KB
    __shared__ float    red[NB * 56];         // head scratch

    const int P[8] = {0, 4, 1, 5, 2, 6, 3, 7};

    // ---- one-time: A fragments + biases into VGPRs, scales prefolded ----
    auto aval = [&](int tt, int k) -> float {
        const int R  = 16 * tt + m16;
        const int rj = R >> 2;
        const int g  = R & 3;
        if (rj >= HID) return 0.f;
        const float sc = (g <= 1) ? -1.44269504f : 2.88539008f;
        float w = 0.f;
        if (g <= 1) {
            if (k < HID)      w = W_hh[(g * HID + rj) * HID + k];
            else if (k >= 56) w = W_ih[(g * HID + rj) * IND + (k - 56)];
        } else if (g == 2) {
            if (k < HID)      w = W_hh[(2 * HID + rj) * HID + k];
        } else {
            if (k >= 56)      w = W_ih[(2 * HID + rj) * IND + (k - 56)];
        }
        return sc * w;
    };

    f16x8 a00, a01, a10, a11;
#pragma unroll
    for (int p = 0; p < 8; ++p) {
        a00[p] = (_Float16)aval(t0, quad * 8 + P[p]);
        a01[p] = (_Float16)aval(t0, 32 + quad * 8 + P[p]);
        a10[p] = (_Float16)aval(t1, quad * 8 + P[p]);
        a11[p] = (_Float16)aval(t1, 32 + quad * 8 + P[p]);
    }

    auto mkbias = [&](int jh) -> f32x4 {
        f32x4 b = {0.f, 0.f, 0.f, 0.f};
        if (jh < HID) {
            b[0] = -1.44269504f * (b_ih[jh] + b_hh[jh]);
            b[1] = -1.44269504f * (b_ih[HID + jh] + b_hh[HID + jh]);
            b[2] =  2.88539008f * b_hh[2 * HID + jh];
            b[3] =  2.88539008f * b_ih[2 * HID + jh];
        }
        return b;
    };
    const f32x4 bias0 = mkbias(jh0);
    const f32x4 bias1 = mkbias(jh1);
    const f32x4 zero4 = {0.f, 0.f, 0.f, 0.f};

    float h0 = 0.f, h1 = 0.f;

    // ---- chunk-0 staging: all threads (startup only) ----
    auto stage_chunk0 = [&]() {
        for (int u = tid; u < NB * CH; u += NTHR) {
            const int n    = u >> 7;
            const int trel = u & (CH - 1);
            const float4* s = (const float4*)(x + ((size_t)(bb * NB + n) * TLEN + trel) * IND);
            const float4 va = s[0];
            const float4 vb = s[1];
            const f16x4 lo = {(_Float16)va.x, (_Float16)vb.x, (_Float16)va.y, (_Float16)vb.y};
            const f16x4 hi = {(_Float16)va.z, (_Float16)vb.z, (_Float16)va.w, (_Float16)vb.w};
            *(f16x4*)&x_frag[0][trel * XTS + n * 8]     = lo;
            *(f16x4*)&x_frag[0][trel * XTS + n * 8 + 4] = hi;
        }
    };

    for (int idx = tid; idx < 2 * 896; idx += NTHR)
        B_lds[idx] = (_Float16)0.f;
    stage_chunk0();
    __syncthreads();

    const int lane8 = lane * 8;                       // halves: lane*16B
    const int wad   = wave * 128 + m16 * 8 + 2 * quad;

    // 5-trans gates, unchained inputs: cc (bias-seeded) + dd (zero-seeded)
    auto gates = [&](const f32x4& cc, const f32x4& dd, float hh) -> float {
        const float g0 = cc[0] + dd[0];
        const float g1 = cc[1] + dd[1];
        const float g2 = cc[2] + dd[2];
        const float g3 = cc[3] + dd[3];
        const float R2 = __builtin_amdgcn_exp2f(g0);
        const float r  = __builtin_amdgcn_rcpf(1.0f + R2);
        const float Z2 = __builtin_amdgcn_exp2f(g1);
        const float E  = __builtin_amdgcn_exp2f(g3 + r * g2);
        const float num = E * (Z2 + hh) + (hh - Z2);
        const float den = (E + 1.0f) * (Z2 + 1.0f);
        return num * __builtin_amdgcn_rcpf(den);
    };

    // stager state (wave 7): 2-deep pipeline, explicit slots (rule 20)
    float4 vaA, vbA, vaB, vbB;
    int nA = 0, tA = 0, nB = 0, tB = 0;
    const float* xsrc_base = x;

    auto stage_issue = [&](int c1, int js, float4& va, float4& vb, int& nn, int& tt) {
        const int u = lane + 64 * js;        // unit in [0, 2048)
        nn = u >> 7;
        tt = u & (CH - 1);
        const float4* s = (const float4*)(xsrc_base +
            ((size_t)(bb * NB + nn) * TLEN + (size_t)c1 * CH + tt) * IND);
        va = s[0];
        vb = s[1];
    };
    auto stage_store = [&](int xb1, const float4& va, const float4& vb, int nn, int tt) {
        const f16x4 lo = {(_Float16)va.x, (_Float16)vb.x, (_Float16)va.y, (_Float16)vb.y};
        const f16x4 hi = {(_Float16)va.z, (_Float16)vb.z, (_Float16)va.w, (_Float16)vb.w};
        *(f16x4*)&x_frag[xb1][tt * XTS + nn * 8]     = lo;
        *(f16x4*)&x_frag[xb1][tt * XTS + nn * 8 + 4] = hi;
    };

    // ---- recurrence: waves 0-6 compute, wave 7 stages; 1 barrier/step ----
    int xb = 0;
    for (int c = 0; c < 4; ++c) {
        const _Float16* xq = &x_frag[xb][m16 * 8];
#pragma unroll 4
        for (int i = 0; i < CH; i += 2) {
            // ---- even step: read buf0, write buf1 ----
            if (wave < 7) {
                _Float16* Bc = &B_lds[0];
                _Float16* Bn = &B_lds[896];
                const f16x8 bf0 = *(const f16x8*)(Bc + lane8);
                const _Float16* p1 = (quad == 3) ? (xq + (size_t)i * XTS) : (Bc + 512 + lane8);
                const f16x8 bf1 = *(const f16x8*)p1;
                f32x4 c0 = __builtin_amdgcn_mfma_f32_16x16x32_f16(a00, bf0, bias0, 0, 0, 0);
                f32x4 d0 = __builtin_amdgcn_mfma_f32_16x16x32_f16(a01, bf1, zero4, 0, 0, 0);
                f32x4 c1 = __builtin_amdgcn_mfma_f32_16x16x32_f16(a10, bf0, bias1, 0, 0, 0);
                f32x4 d1 = __builtin_amdgcn_mfma_f32_16x16x32_f16(a11, bf1, zero4, 0, 0, 0);
                h0 = gates(c0, d0, h0);
                h1 = gates(c1, d1, h1);
                *(f16x2*)(Bn + wad) = f16x2{(_Float16)h0, (_Float16)h1};
            } else if (c < 3) {
                const int js = i >> 1;               // 0..63
                if (js < 34) {
                    if ((js & 1) == 0) {
                        if (js >= 2) stage_store(xb ^ 1, vaA, vbA, nA, tA);
                        if (js < 32) stage_issue(c + 1, js, vaA, vbA, nA, tA);
                    } else {
                        if (js >= 2) stage_store(xb ^ 1, vaB, vbB, nB, tB);
                        if (js < 32) stage_issue(c + 1, js, vaB, vbB, nB, tB);
                    }
                }
            }
            __syncthreads();
            // ---- odd step: read buf1, write buf0 ----
            if (wave < 7) {
                _Float16* Bc = &B_lds[896];
                _Float16* Bn = &B_lds[0];
                const f16x8 bf0 = *(const f16x8*)(Bc + lane8);
                const _Float16* p1 = (quad == 3) ? (xq + (size_t)(i + 1) * XTS) : (Bc + 512 + lane8);
                const f16x8 bf1 = *(const f16x8*)p1;
                f32x4 c0 = __builtin_amdgcn_mfma_f32_16x16x32_f16(a00, bf0, bias0, 0, 0, 0);
                f32x4 d0 = __builtin_amdgcn_mfma_f32_16x16x32_f16(a01, bf1, zero4, 0, 0, 0);
                f32x4 c1 = __builtin_amdgcn_mfma_f32_16x16x32_f16(a10, bf0, bias1, 0, 0, 0);
                f32x4 d1 = __builtin_amdgcn_mfma_f32_16x16x32_f16(a11, bf1, zero4, 0, 0, 0);
                h0 = gates(c0, d0, h0);
                h1 = gates(c1, d1, h1);
                *(f16x2*)(Bn + wad) = f16x2{(_Float16)h0, (_Float16)h1};
            }
            __syncthreads();
        }
        xb ^= 1;
    }

    // ---- head: out[n] = sum_jh h(jh,n) * W_out[jh] + b_out ----
    if (jh0 < HID) red[m16 * 56 + jh0] = h0 * W_out[jh0];
    if (jh1 < HID) red[m16 * 56 + jh1] = h1 * W_out[jh1];
    __syncthreads();
    if (tid < NB) {
        float s = b_out[0];
        for (int j = 0; j < HID; ++j) s += red[tid * 56 + j];
        out[bb * NB + tid] = s;
    }
}

extern "C" void kernel_launch(void* const* d_in, const int* in_sizes, int n_in,
                              void* d_out, int out_size, void* d_ws, size_t ws_size,
                              hipStream_t stream) {
    const float* x     = (const float*)d_in[0];
    const float* W_ih  = (const float*)d_in[1];
    const float* W_hh  = (const float*)d_in[2];
    const float* b_ih  = (const float*)d_in[3];
    const float* b_hh  = (const float*)d_in[4];
    const float* W_out = (const float*)d_in[5];
    const float* b_out = (const float*)d_in[6];
    float* out = (float*)d_out;

    const int B = in_sizes[0] / (TLEN * IND);   // 4096
    gru_mfma11<<<B / NB, NTHR, 0, stream>>>(x, W_ih, W_hh, b_ih, b_hh, W_out, b_out, out);
}